// Round 1
// baseline (1647.870 us; speedup 1.0000x reference)
//
#include <hip/hip_runtime.h>
#include <hip/hip_bf16.h>
#include <stdint.h>

// GEMM: out[M,N] = x[M,K] @ w[N,K]^T * scale
#define MM 8192
#define NN 11008
#define KK 4096

#define BM 128
#define BN 128
#define BK 64

typedef short short8 __attribute__((ext_vector_type(8)));
typedef unsigned short ushort8 __attribute__((ext_vector_type(8)));
typedef float floatx4 __attribute__((ext_vector_type(4)));

__device__ __forceinline__ unsigned short f2bf(float f) {
    unsigned int u = __float_as_uint(f);
    u += 0x7fffu + ((u >> 16) & 1u);   // RNE
    return (unsigned short)(u >> 16);
}

// ---- fp32 -> bf16 conversion (8 elems/thread) ----
__global__ __launch_bounds__(256) void cvt_x_kernel(const float* __restrict__ in,
                                                    unsigned short* __restrict__ out) {
    const size_t i = ((size_t)blockIdx.x * 256 + threadIdx.x) * 8;
    const float4 v0 = *(const float4*)(in + i);
    const float4 v1 = *(const float4*)(in + i + 4);
    ushort8 r;
    r[0] = f2bf(v0.x); r[1] = f2bf(v0.y); r[2] = f2bf(v0.z); r[3] = f2bf(v0.w);
    r[4] = f2bf(v1.x); r[5] = f2bf(v1.y); r[6] = f2bf(v1.z); r[7] = f2bf(v1.w);
    *(ushort8*)(out + i) = r;
}

// ---- int32 (int8-range) -> bf16 conversion, exact (8 elems/thread) ----
__global__ __launch_bounds__(256) void cvt_w_kernel(const int* __restrict__ in,
                                                    unsigned short* __restrict__ out) {
    const size_t i = ((size_t)blockIdx.x * 256 + threadIdx.x) * 8;
    const int4 v0 = *(const int4*)(in + i);
    const int4 v1 = *(const int4*)(in + i + 4);
    ushort8 r;
    r[0] = f2bf((float)v0.x); r[1] = f2bf((float)v0.y);
    r[2] = f2bf((float)v0.z); r[3] = f2bf((float)v0.w);
    r[4] = f2bf((float)v1.x); r[5] = f2bf((float)v1.y);
    r[6] = f2bf((float)v1.z); r[7] = f2bf((float)v1.w);
    *(ushort8*)(out + i) = r;
}

// ---- bf16 MFMA GEMM, m97 structure: 128x128 tile, BK=64, global_load_lds w=16 ----
__global__ __launch_bounds__(256) void gemm_bt_bf16_kernel(
    const unsigned short* __restrict__ A,   // [MM, KK] bf16 bits
    const unsigned short* __restrict__ B,   // [NN, KK] bf16 bits
    const float* __restrict__ scale_p,
    float* __restrict__ C)                  // [MM, NN] fp32
{
    __shared__ unsigned short As[BM * BK];  // 16 KB, row-major [row][k], no padding
    __shared__ unsigned short Bs[BN * BK];  // 16 KB

    const int tid  = threadIdx.x;
    const int lane = tid & 63;
    const int wave = tid >> 6;      // 0..3
    const int wr   = wave >> 1;     // wave row 0..1 (64 rows each)
    const int wc   = wave & 1;      // wave col 0..1 (64 cols each)

    const int bm = blockIdx.y * BM;
    const int bn = blockIdx.x * BN;

    const float scale = *scale_p;

    floatx4 acc[4][4];
#pragma unroll
    for (int i = 0; i < 4; ++i)
#pragma unroll
        for (int j = 0; j < 4; ++j)
            acc[i][j] = (floatx4)0.0f;

    // staging geometry: each global_load_lds call moves 64 lanes x 16B = 1024 B
    // LDS chunk c (1024 B) = tile rows [c*8, c*8+8), 64 bf16 (128 B) per row.
    // lane l -> row c*8 + (l>>3), col (l&7)*8   (matches lds_base + lane*16)
    const int srow = lane >> 3;         // 0..7
    const int scol = (lane & 7) * 8;    // 0,8,...,56

    // MFMA fragment geometry (16x16x32): A[m=lane&15][k=(lane>>4)*8 + j]
    const int mrow = lane & 15;
    const int kq   = (lane >> 4) * 8;

    const unsigned short* gA0 = A + (size_t)bm * KK;
    const unsigned short* gB0 = B + (size_t)bn * KK;

    for (int kt = 0; kt < KK; kt += BK) {
        // ---- stage A and B tiles: 4 rounds x 4 waves x (A+B) ----
#pragma unroll
        for (int r = 0; r < 4; ++r) {
            const int c   = r * 4 + wave;       // chunk 0..15, wave-uniform
            const int row = c * 8 + srow;
            __builtin_amdgcn_global_load_lds(
                (const __attribute__((address_space(1))) void*)(gA0 + (size_t)row * KK + kt + scol),
                (__attribute__((address_space(3))) void*)(As + c * 512),
                16, 0, 0);
            __builtin_amdgcn_global_load_lds(
                (const __attribute__((address_space(1))) void*)(gB0 + (size_t)row * KK + kt + scol),
                (__attribute__((address_space(3))) void*)(Bs + c * 512),
                16, 0, 0);
        }
        __syncthreads();   // compiler emits vmcnt(0) drain before s_barrier

        // ---- compute: 2 K-steps of 32, 16 MFMA each ----
#pragma unroll
        for (int ks = 0; ks < BK; ks += 32) {
            short8 af[4], bf[4];
#pragma unroll
            for (int i = 0; i < 4; ++i)
                af[i] = *(const short8*)(As + (wr * 64 + i * 16 + mrow) * BK + ks + kq);
#pragma unroll
            for (int j = 0; j < 4; ++j)
                bf[j] = *(const short8*)(Bs + (wc * 64 + j * 16 + mrow) * BK + ks + kq);
#pragma unroll
            for (int i = 0; i < 4; ++i)
#pragma unroll
                for (int j = 0; j < 4; ++j)
                    acc[i][j] = __builtin_amdgcn_mfma_f32_16x16x32_bf16(
                        af[i], bf[j], acc[i][j], 0, 0, 0);
        }
        __syncthreads();
    }

    // ---- epilogue: C/D layout col=lane&15, row=(lane>>4)*4+reg ----
    const int crow = (lane >> 4) * 4;
    const int ccol = lane & 15;
#pragma unroll
    for (int i = 0; i < 4; ++i) {
#pragma unroll
        for (int j = 0; j < 4; ++j) {
            const size_t rbase = (size_t)(bm + wr * 64 + i * 16 + crow) * NN
                               + (size_t)(bn + wc * 64 + j * 16 + ccol);
#pragma unroll
            for (int rg = 0; rg < 4; ++rg)
                C[rbase + (size_t)rg * NN] = acc[i][j][rg] * scale;
        }
    }
}

extern "C" void kernel_launch(void* const* d_in, const int* in_sizes, int n_in,
                              void* d_out, int out_size, void* d_ws, size_t ws_size,
                              hipStream_t stream) {
    const float* x     = (const float*)d_in[0];   // [4,2048,4096] fp32
    const int*   w     = (const int*)d_in[1];     // [11008,4096] int32 (int8 range)
    const float* scale = (const float*)d_in[2];   // [1] fp32
    float* out = (float*)d_out;                   // [4,2048,11008] fp32

    // workspace: x_bf16 (64 MiB) then w_bf16 (86 MiB); total 150 MiB
    unsigned short* xb = (unsigned short*)d_ws;
    unsigned short* wb = xb + (size_t)MM * KK;

    // 8 elems/thread, 256 threads/block
    cvt_x_kernel<<<(int)(((size_t)MM * KK) / 2048), 256, 0, stream>>>(x, xb);
    cvt_w_kernel<<<(int)(((size_t)NN * KK) / 2048), 256, 0, stream>>>(w, wb);

    dim3 grid(NN / BN, MM / BM);   // (86, 64)
    gemm_bt_bf16_kernel<<<grid, 256, 0, stream>>>(xb, wb, scale, out);
}